// Round 14
// baseline (113.526 us; speedup 1.0000x reference)
//
#include <hip/hip_runtime.h>
#include <hip/hip_bf16.h>

// USM sharpen, fused 2-kernel MFMA. R13 skeleton + instruction diet:
//   1. v_cvt_pk_bf16_f32 (inline asm) for ALL paired f32->bf16 converts
//      (stage, H-write, epilogue, band build) -- replaces a 5-op bit-twiddle.
//   2. Phase D uses the R12-verified swapped convention (data=A, band=B) so
//      the epilogue does f32x4/uint2 vector IO over x; img/res prefetched
//      before the first barrier. Phase C keeps the R13 convention.
//   3. maskbuf dropped: K2 stages mask from res bf16 via the R9-verified
//      exact bit-compare (u&0x7FFF)>0x3D20  <=>  |res|*255>10 for bf16.
//   K1 (PASS 0): img f32 --[hblur -> H(LDS) -> vblur]--> res bf16
//   K2 (PASS 1): mask(res) --[hblur -> H -> vblur]--> sm; out = img + sm*(sharp-img)
// Geometry (R10..R13-verified): 64x64 tile, stage st[128][136p] bf16 row-major
// (y = y0-33+s, s<122 data + clamp; x = x0-32+c), H[64 x'][136p s] aliased at
// st base (phase-C accs live in regs across the alias barrier), 2 K-slices +
// exact scalar tap corrections. Chunked XCD swizzle (3072 = 8*384, bijective).

typedef __attribute__((ext_vector_type(8))) short bf16x8;
typedef __attribute__((ext_vector_type(4))) float f32x4;

constexpr int IMG = 512, NIMG = 48, K = 51;
constexpr int SP = 136;      // stage pitch: 68 dwords % 32 = 4 -> bank spread
constexpr int YP = 136;      // H pitch (aliased region)
constexpr int SROWS = 128;   // 122 data rows + 6 clamp
constexpr int SDATA = 122;

__device__ __forceinline__ float bf2f(unsigned short u) {
    return __builtin_bit_cast(float, (unsigned)u << 16);
}
__device__ __forceinline__ unsigned cvtpk(float lo, float hi) {  // 2x f32 -> packed bf16, RNE
    unsigned r;
    asm("v_cvt_pk_bf16_f32 %0, %1, %2" : "=v"(r) : "v"(lo), "v"(hi));
    return r;
}
__device__ __forceinline__ int refl(int i) {
    i = i < 0 ? -i : i;
    return i >= IMG ? 2 * IMG - 2 - i : i;
}

template <int PASS>  // 0: img -> res ; 1: res -> out
__global__ __launch_bounds__(512, 8) void usm_kern(const float* __restrict__ img,
                                                   unsigned short* __restrict__ resbuf,
                                                   float* __restrict__ out,
                                                   const float* __restrict__ k1d) {
    __shared__ unsigned short st[SROWS * SP];      // 34816 B; H aliases its base
    unsigned short* const Hl = st;                 // H[64][YP] = 17408 B < st

    const int tid = threadIdx.x, lane = tid & 63;
    const int wv = __builtin_amdgcn_readfirstlane(tid >> 6);
    const int m16 = lane & 15, g = lane >> 4;

    const int id = blockIdx.x;
    const int sw = (id & 7) * 384 + (id >> 3);  // bijective XCD swizzle: 3072 = 8*384
    const int bz = sw >> 6, r6 = sw & 63, byy = r6 >> 3, bxx = r6 & 7;
    const int x0 = bxx * 64, y0 = byy * 64;
    const size_t base = (size_t)bz * (IMG * IMG);
    const float* __restrict__ imgb = img + base;
    unsigned short* __restrict__ resb = resbuf + base;
    float* __restrict__ outb = out + base;

    // ---- W bands in registers: a_v[rs][j]=g[32rs+8g+j-m16], a_h = idx+1 ----
    bf16x8 a_v[2], a_h[2];
#pragma unroll
    for (int rs = 0; rs < 2; ++rs) {
        float gt[9];
#pragma unroll
        for (int e = 0; e < 9; ++e) {
            const int t = 32 * rs + 8 * g + e - m16;
            gt[e] = ((unsigned)t < (unsigned)K) ? k1d[t] : 0.f;
        }
        uint4 uv, uh;
        uv.x = cvtpk(gt[0], gt[1]); uv.y = cvtpk(gt[2], gt[3]);
        uv.z = cvtpk(gt[4], gt[5]); uv.w = cvtpk(gt[6], gt[7]);
        uh.x = cvtpk(gt[1], gt[2]); uh.y = cvtpk(gt[3], gt[4]);
        uh.z = cvtpk(gt[5], gt[6]); uh.w = cvtpk(gt[7], gt[8]);
        a_v[rs] = __builtin_bit_cast(bf16x8, uv);
        a_h[rs] = __builtin_bit_cast(bf16x8, uh);
    }
    const float gg0 = k1d[0], gg49 = k1d[49], gg50 = k1d[50];  // uniform -> SGPR

    // ---- stage 128 rows x 128 cols (row-dense b128 writes) ----
    const bool xedge = (bxx == 0) | (bxx == 7);
    const int r0t = tid >> 4, c8 = (tid & 15) * 8;
#pragma unroll
    for (int j = 0; j < 4; ++j) {
        const int s = r0t + 32 * j;
        const int rowo = refl(y0 - 33 + min(s, SDATA - 1)) * IMG + (x0 - 32 + c8);
        unsigned pk[4];
        if (PASS == 0) {
            float v[8];
            if (!xedge) {
                const f32x4 f0 = *(const f32x4*)&imgb[rowo];
                const f32x4 f1 = *(const f32x4*)&imgb[rowo + 4];
#pragma unroll
                for (int e = 0; e < 4; ++e) { v[e] = f0[e]; v[e + 4] = f1[e]; }
            } else {
                const int rb = rowo - (x0 - 32 + c8);
#pragma unroll
                for (int e = 0; e < 8; ++e) v[e] = imgb[rb + refl(x0 - 32 + c8 + e)];
            }
#pragma unroll
            for (int w = 0; w < 4; ++w) pk[w] = cvtpk(v[2 * w], v[2 * w + 1]);
        } else {
            unsigned rw[4];
            if (!xedge) {
                const uint4 q4 = *(const uint4*)&resb[rowo];
                rw[0] = q4.x; rw[1] = q4.y; rw[2] = q4.z; rw[3] = q4.w;
            } else {
                const int rb = rowo - (x0 - 32 + c8);
#pragma unroll
                for (int w = 0; w < 4; ++w) {
                    const unsigned short e0 = resb[rb + refl(x0 - 32 + c8 + 2 * w)];
                    const unsigned short e1 = resb[rb + refl(x0 - 32 + c8 + 2 * w + 1)];
                    rw[w] = (unsigned)e0 | ((unsigned)e1 << 16);
                }
            }
#pragma unroll
            for (int w = 0; w < 4; ++w) {  // mask(|res|*255>10): exact bf16 bit-compare
                const unsigned lo = ((rw[w] & 0x7FFFu) > 0x3D20u) ? 0x3F80u : 0u;
                const unsigned hi = (((rw[w] >> 16) & 0x7FFFu) > 0x3D20u) ? 0x3F80u : 0u;
                pk[w] = lo | (hi << 16);
            }
        }
        *(uint4*)&st[s * SP + c8] = make_uint4(pk[0], pk[1], pk[2], pk[3]);
    }

    // ---- prefetch epilogue operands (consumed after all barriers) ----
    f32x4 ivp[2];
    uint2 rvp[2];
#pragma unroll
    for (int k2 = 0; k2 < 2; ++k2) {
        const int t = wv + 8 * k2;
        const int xs = t & 3, ys = t >> 2;
        const int di = (y0 + 16 * ys + m16) * IMG + (x0 + 16 * xs + 4 * g);
        ivp[k2] = *(const f32x4*)&imgb[di];
        if (PASS == 1) rvp[k2] = *(const uint2*)&resb[di];
    }
    __syncthreads();

    // ---- phase C: hblur, accumulators in registers (R13 convention) ----
    f32x4 cacc[4];
#pragma unroll
    for (int k4 = 0; k4 < 4; ++k4) {
        const int t = wv + 8 * k4;
        const int xs = t & 3, yt = t >> 2;
        const int n = 16 * yt + m16;  // B col = stage row s
        f32x4 acc = {0.f, 0.f, 0.f, 0.f};
#pragma unroll
        for (int rs = 0; rs < 2; ++rs) {
            const bf16x8 b = *(const bf16x8*)&st[n * SP + 16 * xs + 8 + 32 * rs + 8 * g];
            acc = __builtin_amdgcn_mfma_f32_16x16x32_bf16(a_h[rs], b, acc, 0, 0, 0);
        }
        if (g == 0) acc[0] = fmaf(gg0,  bf2f(st[n * SP + 16 * xs + 7]),  acc[0]);  // i=0,  t=0
        if (g == 3) acc[3] = fmaf(gg50, bf2f(st[n * SP + 16 * xs + 72]), acc[3]);  // i=15, t=50
        cacc[k4] = acc;
    }
    __syncthreads();  // st fully consumed; H may overwrite its base

    // ---- H write (aliased into st), packed converts ----
#pragma unroll
    for (int k4 = 0; k4 < 4; ++k4) {
        const int t = wv + 8 * k4;
        const int xs = t & 3, yt = t >> 2;
        const int n = 16 * yt + m16;
        const unsigned u01 = cvtpk(cacc[k4][0], cacc[k4][1]);
        const unsigned u23 = cvtpk(cacc[k4][2], cacc[k4][3]);
        Hl[(16 * xs + 4 * g + 0) * YP + n] = (unsigned short)u01;
        Hl[(16 * xs + 4 * g + 1) * YP + n] = (unsigned short)(u01 >> 16);
        Hl[(16 * xs + 4 * g + 2) * YP + n] = (unsigned short)u23;
        Hl[(16 * xs + 4 * g + 3) * YP + n] = (unsigned short)(u23 >> 16);
    }
    __syncthreads();

    // ---- phase D: vblur (R12-verified swapped convention) + vector epilogue ----
#pragma unroll
    for (int k2 = 0; k2 < 2; ++k2) {
        const int t = wv + 8 * k2;
        const int xs = t & 3, ys = t >> 2;
        f32x4 acc = {0.f, 0.f, 0.f, 0.f};
#pragma unroll
        for (int rs = 0; rs < 2; ++rs) {
            const bf16x8 ah = *(const bf16x8*)&Hl[(16 * xs + m16) * YP + 16 * ys + 8 + 32 * rs + 8 * g];
            acc = __builtin_amdgcn_mfma_f32_16x16x32_bf16(ah, a_v[rs], acc, 0, 0, 0);
        }
        if (m16 == 14) {  // j=14, t=50 @ s=16ys+72
#pragma unroll
            for (int q = 0; q < 4; ++q)
                acc[q] = fmaf(gg50, bf2f(Hl[(16 * xs + 4 * g + q) * YP + 16 * ys + 72]), acc[q]);
        }
        if (m16 == 15) {  // j=15, t=49,50 @ s=16ys+72,73
#pragma unroll
            for (int q = 0; q < 4; ++q) {
                const int hb = (16 * xs + 4 * g + q) * YP + 16 * ys;
                acc[q] = fmaf(gg49, bf2f(Hl[hb + 72]), fmaf(gg50, bf2f(Hl[hb + 73]), acc[q]));
            }
        }
        const int di = (y0 + 16 * ys + m16) * IMG + (x0 + 16 * xs + 4 * g);
        const f32x4 iv = ivp[k2];
        if (PASS == 0) {
            float rv[4];
#pragma unroll
            for (int q = 0; q < 4; ++q) rv[q] = iv[q] - acc[q];
            *(uint2*)&resb[di] = make_uint2(cvtpk(rv[0], rv[1]), cvtpk(rv[2], rv[3]));
        } else {
            f32x4 o;
#pragma unroll
            for (int q = 0; q < 4; ++q) {
                const unsigned rw = (q < 2) ? rvp[k2].x : rvp[k2].y;
                const float rvq = bf2f((unsigned short)(rw >> ((q & 1) * 16)));
                float sharp = fmaf(0.5f, rvq, iv[q]);
                sharp = fminf(fmaxf(sharp, 0.f), 1.f);
                o[q] = fmaf(acc[q], sharp - iv[q], iv[q]);  // img + sm*(sharp-img)
            }
            *(f32x4*)&outb[di] = o;
        }
    }
}

extern "C" void kernel_launch(void* const* d_in, const int* in_sizes, int n_in,
                              void* d_out, int out_size, void* d_ws, size_t ws_size,
                              hipStream_t stream) {
    (void)in_sizes; (void)n_in; (void)out_size; (void)ws_size;
    const float* img = (const float*)d_in[0];
    const float* k1d = (const float*)d_in[1];
    float* out = (float*)d_out;
    unsigned short* rs = (unsigned short*)d_ws;  // 25165824 B

    const dim3 grid(NIMG * 64);  // 3072 blocks x 512 threads

    usm_kern<0><<<grid, 512, 0, stream>>>(img, rs, out, k1d);
    usm_kern<1><<<grid, 512, 0, stream>>>(img, rs, out, k1d);
}

// Round 16
// 100.586 us; speedup vs baseline: 1.1287x; 1.1287x over previous
//
#include <hip/hip_runtime.h>
#include <hip/hip_bf16.h>

// USM sharpen, fused 2-kernel MFMA. R13 phase code + multi-tile pipelined blocks.
// R15 bugfix: pipeline loads tile i+1's NEW window rows s' in [58,122) -- R15
// loaded [64,128) and left s' in [58,64) as stale clamp data (absmax 3.9e-2).
//   - 768 blocks (3/CU resident, zero tail), each does 4 y-consecutive 64x64
//     tiles of one (image, x-column, y-half).
//   - Circular 128-row stage buffer: consecutive tiles share 64 halo rows;
//     64 new rows load per tile (stage reads 512 -> 320 rows/block).
//   - T14 write-late: next tile's rows loaded RAW to regs at iter start,
//     packed + ds_written after the post-C barrier (overlaps phase D).
//   - H in its own LDS region; phase C writes H inline. 2 barriers/tile.
//   K1 (PASS 0): img f32 --[hblur -> H(LDS) -> vblur]--> res bf16
//   K2 (PASS 1): mask(res) --[hblur -> H -> vblur]--> sm; out = img + sm*(sharp-img)
// Phase C/D math identical to R13 (verified): 2 K-slices, g-predicated scalar
// corrections, R7 fragment convention. Mask via exact bf16 bit-compare.
// Slot map: tile i window row s -> slot (s + 64*i) & 127. Window rows >=122
// are dead (feed only H cols >121, which phase D never reads); their slots
// hold stale-but-finite data, multiplied only by in-band weights for n<=121.

typedef __attribute__((ext_vector_type(8))) short bf16x8;
typedef __attribute__((ext_vector_type(4))) float f32x4;

constexpr int IMG = 512, NIMG = 48, K = 51;
constexpr int SP = 136;      // stage pitch: 68 dwords % 32 = 4 -> bank spread
constexpr int YP = 136;      // H pitch
constexpr int SDATA = 122;   // real data rows per window (33 + 64 + 25)

__device__ __forceinline__ float bf2f(unsigned short u) {
    return __builtin_bit_cast(float, (unsigned)u << 16);
}
__device__ __forceinline__ unsigned short f2bf(float f) {
    unsigned u = __builtin_bit_cast(unsigned, f);
    u += 0x7FFF + ((u >> 16) & 1);  // RNE, finite inputs only
    return (unsigned short)(u >> 16);
}
__device__ __forceinline__ int refl(int i) {
    i = i < 0 ? -i : i;
    return i >= IMG ? 2 * IMG - 2 - i : i;
}

template <int PASS>  // 0: img -> res ; 1: res -> out
__global__ __launch_bounds__(512, 6) void usm_kern(const float* __restrict__ img,
                                                   unsigned short* __restrict__ resbuf,
                                                   float* __restrict__ out,
                                                   const float* __restrict__ k1d) {
    __shared__ unsigned short st[128 * SP];  // 34816 B circular stage
    __shared__ unsigned short Hl[64 * YP];   // 17408 B

    const int tid = threadIdx.x, lane = tid & 63;
    const int wv = __builtin_amdgcn_readfirstlane(tid >> 6);
    const int m16 = lane & 15, g = lane >> 4;

    // 768 blocks: XCD-chunked; within chunk bxx fastest -> x-halo L2 sharing
    const int id = blockIdx.x;
    const int col = (id & 7) * 96 + (id >> 3);           // [0,768)
    const int bz = col >> 4, rr = col & 15, half = rr >> 3, bxx = rr & 7;
    const int x0 = bxx * 64, ybase = half * 256;
    const size_t base = (size_t)bz * (IMG * IMG);
    const float* __restrict__ imgb = img + base;
    unsigned short* __restrict__ resb = resbuf + base;
    float* __restrict__ outb = out + base;

    // ---- W bands in registers: a_v[rs][j]=g[32rs+8g+j-m16], a_h = idx+1 ----
    bf16x8 a_v[2], a_h[2];
#pragma unroll
    for (int rs = 0; rs < 2; ++rs) {
        float gt[9];
#pragma unroll
        for (int e = 0; e < 9; ++e) {
            const int t = 32 * rs + 8 * g + e - m16;
            gt[e] = ((unsigned)t < (unsigned)K) ? k1d[t] : 0.f;
        }
#pragma unroll
        for (int j = 0; j < 8; ++j) {
            a_v[rs][j] = (short)f2bf(gt[j]);
            a_h[rs][j] = (short)f2bf(gt[j + 1]);
        }
    }
    const float gg0 = k1d[0], gg49 = k1d[49], gg50 = k1d[50];

    const bool xedge = (bxx == 0) | (bxx == 7);
    const int r0t = tid >> 4, c8 = (tid & 15) * 8, xoff = x0 - 32 + c8;

    // ---- prologue: stage tile 0's full 128-row window (slots = s) ----
#pragma unroll
    for (int s4 = 0; s4 < 4; ++s4) {
        const int s = r0t + 32 * s4;
        const int rowb = refl(ybase - 33 + min(s, SDATA - 1)) * IMG;
        unsigned pk[4];
        if (PASS == 0) {
            float v[8];
            if (!xedge) {
                const f32x4 f0 = *(const f32x4*)&imgb[rowb + xoff];
                const f32x4 f1 = *(const f32x4*)&imgb[rowb + xoff + 4];
#pragma unroll
                for (int e = 0; e < 4; ++e) { v[e] = f0[e]; v[e + 4] = f1[e]; }
            } else {
#pragma unroll
                for (int e = 0; e < 8; ++e) v[e] = imgb[rowb + refl(xoff + e)];
            }
#pragma unroll
            for (int w = 0; w < 4; ++w)
                pk[w] = (unsigned)f2bf(v[2 * w]) | ((unsigned)f2bf(v[2 * w + 1]) << 16);
        } else {
            unsigned rw[4];
            if (!xedge) {
                const uint4 q4 = *(const uint4*)&resb[rowb + xoff];
                rw[0] = q4.x; rw[1] = q4.y; rw[2] = q4.z; rw[3] = q4.w;
            } else {
#pragma unroll
                for (int w = 0; w < 4; ++w) {
                    const unsigned short e0 = resb[rowb + refl(xoff + 2 * w)];
                    const unsigned short e1 = resb[rowb + refl(xoff + 2 * w + 1)];
                    rw[w] = (unsigned)e0 | ((unsigned)e1 << 16);
                }
            }
#pragma unroll
            for (int w = 0; w < 4; ++w) {  // mask(|res|*255>10): exact bf16 bit-compare
                const unsigned lo = ((rw[w] & 0x7FFFu) > 0x3D20u) ? 0x3F80u : 0u;
                const unsigned hi = (((rw[w] >> 16) & 0x7FFFu) > 0x3D20u) ? 0x3F80u : 0u;
                pk[w] = lo | (hi << 16);
            }
        }
        *(uint4*)&st[s * SP + c8] = make_uint4(pk[0], pk[1], pk[2], pk[3]);
    }
    __syncthreads();

#pragma unroll 1
    for (int i = 0; i < 4; ++i) {
        const int y0 = ybase + 64 * i;
        const int off = (i & 1) << 6;  // slot offset of tile i's window

        // ---- issue next tile's 64 NEW rows (s' in [58,122)) RAW into regs ----
        f32x4 nfa0, nfa1, nfb0, nfb1;  // K1: rows A,B x 2 halves
        uint4 nma, nmb;                // K2
        if (i < 3) {
            const int y0n = y0 + 64;
            const int rA = refl(y0n + 25 + r0t) * IMG;   // s' = 58 + r0t in [58,90)
            const int rB = refl(y0n + 57 + r0t) * IMG;   // s' = 90 + r0t in [90,122)
            if (PASS == 0) {
                if (!xedge) {
                    nfa0 = *(const f32x4*)&imgb[rA + xoff];
                    nfa1 = *(const f32x4*)&imgb[rA + xoff + 4];
                    nfb0 = *(const f32x4*)&imgb[rB + xoff];
                    nfb1 = *(const f32x4*)&imgb[rB + xoff + 4];
                } else {
#pragma unroll
                    for (int e = 0; e < 4; ++e) {
                        nfa0[e] = imgb[rA + refl(xoff + e)];
                        nfa1[e] = imgb[rA + refl(xoff + 4 + e)];
                        nfb0[e] = imgb[rB + refl(xoff + e)];
                        nfb1[e] = imgb[rB + refl(xoff + 4 + e)];
                    }
                }
            } else {
                if (!xedge) {
                    nma = *(const uint4*)&resb[rA + xoff];
                    nmb = *(const uint4*)&resb[rB + xoff];
                } else {
                    unsigned wa[4], wb[4];
#pragma unroll
                    for (int w = 0; w < 4; ++w) {
                        wa[w] = (unsigned)resb[rA + refl(xoff + 2 * w)] |
                                ((unsigned)resb[rA + refl(xoff + 2 * w + 1)] << 16);
                        wb[w] = (unsigned)resb[rB + refl(xoff + 2 * w)] |
                                ((unsigned)resb[rB + refl(xoff + 2 * w + 1)] << 16);
                    }
                    nma = make_uint4(wa[0], wa[1], wa[2], wa[3]);
                    nmb = make_uint4(wb[0], wb[1], wb[2], wb[3]);
                }
            }
        }

        // ---- phase C: hblur -> Hl inline (R13 math, circular stage rows) ----
#pragma unroll
        for (int k4 = 0; k4 < 4; ++k4) {
            const int t = wv + 8 * k4;
            const int xs = t & 3, yt = t >> 2;
            const int n = 16 * yt + m16;                    // window row / H col
            const int sr = ((16 * yt + off) & 127) + m16;   // physical slot row
            f32x4 acc = {0.f, 0.f, 0.f, 0.f};
#pragma unroll
            for (int rs = 0; rs < 2; ++rs) {
                const bf16x8 b = *(const bf16x8*)&st[sr * SP + 16 * xs + 8 + 32 * rs + 8 * g];
                acc = __builtin_amdgcn_mfma_f32_16x16x32_bf16(a_h[rs], b, acc, 0, 0, 0);
            }
            if (g == 0) acc[0] = fmaf(gg0,  bf2f(st[sr * SP + 16 * xs + 7]),  acc[0]);  // i=0,  t=0
            if (g == 3) acc[3] = fmaf(gg50, bf2f(st[sr * SP + 16 * xs + 72]), acc[3]);  // i=15, t=50
#pragma unroll
            for (int q = 0; q < 4; ++q)
                Hl[(16 * xs + 4 * g + q) * YP + n] = f2bf(acc[q]);
        }
        __syncthreads();  // H ready; all st readers of tile i done

        // ---- write next tile's rows (pack now; vmcnt waits land here) ----
        if (i < 3) {
            const int noff = (~i & 1) << 6;  // slot offset of tile i+1
            const int slA = ((58 + r0t + noff) & 127) * SP + c8;
            const int slB = ((90 + r0t + noff) & 127) * SP + c8;
            unsigned pa[4], pb[4];
            if (PASS == 0) {
                pa[0] = (unsigned)f2bf(nfa0[0]) | ((unsigned)f2bf(nfa0[1]) << 16);
                pa[1] = (unsigned)f2bf(nfa0[2]) | ((unsigned)f2bf(nfa0[3]) << 16);
                pa[2] = (unsigned)f2bf(nfa1[0]) | ((unsigned)f2bf(nfa1[1]) << 16);
                pa[3] = (unsigned)f2bf(nfa1[2]) | ((unsigned)f2bf(nfa1[3]) << 16);
                pb[0] = (unsigned)f2bf(nfb0[0]) | ((unsigned)f2bf(nfb0[1]) << 16);
                pb[1] = (unsigned)f2bf(nfb0[2]) | ((unsigned)f2bf(nfb0[3]) << 16);
                pb[2] = (unsigned)f2bf(nfb1[0]) | ((unsigned)f2bf(nfb1[1]) << 16);
                pb[3] = (unsigned)f2bf(nfb1[2]) | ((unsigned)f2bf(nfb1[3]) << 16);
            } else {
                const unsigned wa[4] = {nma.x, nma.y, nma.z, nma.w};
                const unsigned wb[4] = {nmb.x, nmb.y, nmb.z, nmb.w};
#pragma unroll
                for (int w = 0; w < 4; ++w) {
                    pa[w] = (((wa[w] & 0x7FFFu) > 0x3D20u) ? 0x3F80u : 0u) |
                            ((((wa[w] >> 16) & 0x7FFFu) > 0x3D20u) ? 0x3F800000u : 0u);
                    pb[w] = (((wb[w] & 0x7FFFu) > 0x3D20u) ? 0x3F80u : 0u) |
                            ((((wb[w] >> 16) & 0x7FFFu) > 0x3D20u) ? 0x3F800000u : 0u);
                }
            }
            *(uint4*)&st[slA] = make_uint4(pa[0], pa[1], pa[2], pa[3]);
            *(uint4*)&st[slB] = make_uint4(pb[0], pb[1], pb[2], pb[3]);
        }

        // ---- phase D: vblur + fused epilogue (R13 math, H not circular) ----
#pragma unroll
        for (int k2 = 0; k2 < 2; ++k2) {
            const int t = wv + 8 * k2;
            const int xs2 = t & 3, ys = t >> 2;
            const int xl = 16 * xs2 + m16;
            f32x4 acc = {0.f, 0.f, 0.f, 0.f};
#pragma unroll
            for (int rs = 0; rs < 2; ++rs) {
                const bf16x8 b = *(const bf16x8*)&Hl[xl * YP + 16 * ys + 8 + 32 * rs + 8 * g];
                acc = __builtin_amdgcn_mfma_f32_16x16x32_bf16(a_v[rs], b, acc, 0, 0, 0);
            }
            if (g == 3) {
                const float h72 = bf2f(Hl[xl * YP + 16 * ys + 72]);
                const float h73 = bf2f(Hl[xl * YP + 16 * ys + 73]);
                acc[2] = fmaf(gg50, h72, acc[2]);                   // i=14, t=50
                acc[3] = fmaf(gg49, h72, fmaf(gg50, h73, acc[3]));  // i=15, t=49,50
            }
            const int yl0 = 16 * ys + 4 * g;
#pragma unroll
            for (int q = 0; q < 4; ++q) {
                const int di = (y0 + yl0 + q) * IMG + (x0 + xl);
                const float iv = imgb[di];  // L2-hot (staged this block)
                if (PASS == 0) {
                    resb[di] = f2bf(iv - acc[q]);
                } else {
                    const float rv = bf2f(resb[di]);
                    float sharp = fmaf(0.5f, rv, iv);
                    sharp = fminf(fmaxf(sharp, 0.f), 1.f);
                    outb[di] = fmaf(acc[q], sharp - iv, iv);  // img + sm*(sharp-img)
                }
            }
        }
        __syncthreads();  // stage(i+1) ready; D readers of Hl done
    }
}

extern "C" void kernel_launch(void* const* d_in, const int* in_sizes, int n_in,
                              void* d_out, int out_size, void* d_ws, size_t ws_size,
                              hipStream_t stream) {
    (void)in_sizes; (void)n_in; (void)out_size; (void)ws_size;
    const float* img = (const float*)d_in[0];
    const float* k1d = (const float*)d_in[1];
    float* out = (float*)d_out;
    unsigned short* rs = (unsigned short*)d_ws;  // 25165824 B

    const dim3 grid(NIMG * 16);  // 768 blocks x 512 threads, 4 tiles each

    usm_kern<0><<<grid, 512, 0, stream>>>(img, rs, out, k1d);
    usm_kern<1><<<grid, 512, 0, stream>>>(img, rs, out, k1d);
}